// Round 9
// baseline (325.127 us; speedup 1.0000x reference)
//
#include <hip/hip_runtime.h>

#define NN 50000
#define NE 800000
#define HD 128
#define NG 256
#define ELLW 64
#define NVX 8
#define RNG (NN / NVX)   /* 6250 */
#define EPT 4

// ---------- build: vXCD-partitioned deg count + ELL fill + batch count ----------
// Block handles only dst in its 1/8 node range (c = blockIdx&7 -> same XCD under
// round-robin dispatch), so ELL/deg cache lines are written from one XCD's L2
// and write-combine instead of bouncing.
__global__ __launch_bounds__(256) void fill_k(const int* __restrict__ src, const int* __restrict__ dst,
                                              const int* __restrict__ batch,
                                              int* __restrict__ deg, ushort* __restrict__ ell,
                                              int* __restrict__ cnt) {
  int c = blockIdx.x & (NVX - 1);
  int sb = blockIdx.x >> 3;
  int base = sb * (256 * EPT) + threadIdx.x;
  int lo = c * RNG;
#pragma unroll
  for (int k = 0; k < EPT; ++k) {
    int e = base + k * 256;
    if (e < NE) {
      int d = dst[e];
      unsigned r = (unsigned)(d - lo);
      if (r < (unsigned)RNG) {
        int p = atomicAdd(&deg[d], 1);
        if (p < ELLW) ell[(size_t)d * ELLW + p] = (ushort)src[e];
      }
    }
  }
  if (c == 0) {
#pragma unroll
    for (int k = 0; k < EPT; ++k) {
      int e = base + k * 256;
      if (e < NN) atomicAdd(&cnt[batch[e]], 1);
    }
  }
}

__global__ __launch_bounds__(256) void dinv_k(const int* __restrict__ deg, float* __restrict__ dinv) {
  int n = blockIdx.x * 256 + threadIdx.x;
  if (n < NN) dinv[n] = 1.0f / sqrtf((float)(deg[n] + 1));  // +1: self-loop
}

// ---------- GEMM: out[r][c] = (sum_k X[r][k]*W[k][c]) * dinv[r] ----------
__global__ __launch_bounds__(256) void gemm128_k(const float* __restrict__ X, const float* __restrict__ W,
                                                 const float* __restrict__ dinv, float* __restrict__ out) {
  __shared__ float xs[64 * 128];
  int t = threadIdx.x;
  int row0 = blockIdx.x * 64;
  const float4* X4 = (const float4*)X;
  float4* xs4 = (float4*)xs;
#pragma unroll
  for (int i = 0; i < 8; ++i) {
    int idx = i * 256 + t;                 // 0..2047
    int r = row0 + (idx >> 5);
    if (r > NN - 1) r = NN - 1;
    xs4[idx] = X4[(size_t)r * 32 + (idx & 31)];
  }
  __syncthreads();
  int lane = t & 31;                        // cols lane*4 .. +3
  int rg = t >> 5;                          // rows rg*8 .. +7
  const float4* W4 = (const float4*)W;
  float acc[8][4] = {};
#pragma unroll 2
  for (int k = 0; k < 128; k += 4) {
    float4 b[4];
#pragma unroll
    for (int kk = 0; kk < 4; ++kk) b[kk] = W4[(size_t)(k + kk) * 32 + lane];
    float4 a[8];
#pragma unroll
    for (int i = 0; i < 8; ++i) a[i] = *(const float4*)&xs[(rg * 8 + i) * 128 + k];
#pragma unroll
    for (int i = 0; i < 8; ++i) {
      acc[i][0] = fmaf(a[i].x, b[0].x, acc[i][0]);
      acc[i][1] = fmaf(a[i].x, b[0].y, acc[i][1]);
      acc[i][2] = fmaf(a[i].x, b[0].z, acc[i][2]);
      acc[i][3] = fmaf(a[i].x, b[0].w, acc[i][3]);
      acc[i][0] = fmaf(a[i].y, b[1].x, acc[i][0]);
      acc[i][1] = fmaf(a[i].y, b[1].y, acc[i][1]);
      acc[i][2] = fmaf(a[i].y, b[1].z, acc[i][2]);
      acc[i][3] = fmaf(a[i].y, b[1].w, acc[i][3]);
      acc[i][0] = fmaf(a[i].z, b[2].x, acc[i][0]);
      acc[i][1] = fmaf(a[i].z, b[2].y, acc[i][1]);
      acc[i][2] = fmaf(a[i].z, b[2].z, acc[i][2]);
      acc[i][3] = fmaf(a[i].z, b[2].w, acc[i][3]);
      acc[i][0] = fmaf(a[i].w, b[3].x, acc[i][0]);
      acc[i][1] = fmaf(a[i].w, b[3].y, acc[i][1]);
      acc[i][2] = fmaf(a[i].w, b[3].z, acc[i][2]);
      acc[i][3] = fmaf(a[i].w, b[3].w, acc[i][3]);
    }
  }
#pragma unroll
  for (int i = 0; i < 8; ++i) {
    int r = row0 + rg * 8 + i;
    if (r < NN) {
      float d = dinv[r];
      float4 o = make_float4(acc[i][0] * d, acc[i][1] * d, acc[i][2] * d, acc[i][3] * d);
      *(float4*)&out[(size_t)r * 128 + lane * 4] = o;
    }
  }
}

// ---------- pull aggregation (R8-measured structure, unchanged) ----------
template <bool POOL>
__global__ __launch_bounds__(256) void aggregate_k(const float* __restrict__ tmp2,
                                                   const ushort* __restrict__ ell, const int* __restrict__ deg,
                                                   const float* __restrict__ dinv, const float* __restrict__ bias,
                                                   float* __restrict__ out,
                                                   const int* __restrict__ batch, float* __restrict__ sums) {
  int wid = threadIdx.x >> 6;
  int lane = threadIdx.x & 63;
  int n = blockIdx.x * 4 + wid;
  if (n >= NN) return;
  const float2* T2 = (const float2*)tmp2;
  float2 acc = T2[(size_t)n * 64 + lane];  // self-loop term (already *dinv[n])
  int d = deg[n]; if (d > ELLW) d = ELLW;
  int idx = (int)ell[(size_t)n * ELLW + lane];  // lanes >= d hold garbage, never selected
  int j = 0;
  for (; j + 8 <= d; j += 8) {
    int s0 = __shfl(idx, j);
    int s1 = __shfl(idx, j + 1);
    int s2 = __shfl(idx, j + 2);
    int s3 = __shfl(idx, j + 3);
    int s4 = __shfl(idx, j + 4);
    int s5 = __shfl(idx, j + 5);
    int s6 = __shfl(idx, j + 6);
    int s7 = __shfl(idx, j + 7);
    float2 v0 = T2[(size_t)s0 * 64 + lane];
    float2 v1 = T2[(size_t)s1 * 64 + lane];
    float2 v2 = T2[(size_t)s2 * 64 + lane];
    float2 v3 = T2[(size_t)s3 * 64 + lane];
    float2 v4 = T2[(size_t)s4 * 64 + lane];
    float2 v5 = T2[(size_t)s5 * 64 + lane];
    float2 v6 = T2[(size_t)s6 * 64 + lane];
    float2 v7 = T2[(size_t)s7 * 64 + lane];
    acc.x += ((v0.x + v1.x) + (v2.x + v3.x)) + ((v4.x + v5.x) + (v6.x + v7.x));
    acc.y += ((v0.y + v1.y) + (v2.y + v3.y)) + ((v4.y + v5.y) + (v6.y + v7.y));
  }
  for (; j < d; ++j) {
    int s0 = __shfl(idx, j);
    float2 v = T2[(size_t)s0 * 64 + lane];
    acc.x += v.x; acc.y += v.y;
  }
  float dv = dinv[n];
  float2 bb = ((const float2*)bias)[lane];
  float2 o;
  o.x = fmaxf(fmaf(acc.x, dv, bb.x), 0.0f);
  o.y = fmaxf(fmaf(acc.y, dv, bb.y), 0.0f);
  if (POOL) {
    int g = batch[n];
    float* sp = &sums[(size_t)g * HD + lane * 2];
    atomicAdd(sp + 0, o.x);
    atomicAdd(sp + 1, o.y);
  } else {
    ((float2*)out)[(size_t)n * 64 + lane] = o;
  }
}

// ---------- head ----------
__global__ __launch_bounds__(128) void mlp_k(const float* __restrict__ sums, const int* __restrict__ cnt,
                                             const float* __restrict__ Wl1, const float* __restrict__ bl1,
                                             const float* __restrict__ Wl2, const float* __restrict__ bl2,
                                             float* __restrict__ out) {
  __shared__ float gs[128];
  __shared__ float red[128];
  int g = blockIdx.x, t = threadIdx.x;
  int c = cnt[g]; if (c < 1) c = 1;
  gs[t] = sums[(size_t)g * HD + t] / (float)c;
  __syncthreads();
  float acc = bl1[t];
#pragma unroll 8
  for (int k = 0; k < 128; ++k) acc = fmaf(gs[k], Wl1[k * HD + t], acc);
  acc = fmaxf(acc, 0.0f);
  red[t] = acc * Wl2[t];
  __syncthreads();
  for (int off = 64; off > 0; off >>= 1) {
    if (t < off) red[t] += red[t + off];
    __syncthreads();
  }
  if (t == 0) out[g] = red[0] + bl2[0];
}

extern "C" void kernel_launch(void* const* d_in, const int* in_sizes, int n_in,
                              void* d_out, int out_size, void* d_ws, size_t ws_size,
                              hipStream_t stream) {
  const float* x   = (const float*)d_in[0];
  const int*   edge = (const int*)d_in[1];
  const int*   batch = (const int*)d_in[2];
  const float* W1  = (const float*)d_in[3];
  const float* b1  = (const float*)d_in[4];
  const float* W2  = (const float*)d_in[5];
  const float* b2  = (const float*)d_in[6];
  const float* Wl1 = (const float*)d_in[7];
  const float* bl1 = (const float*)d_in[8];
  const float* Wl2 = (const float*)d_in[9];
  const float* bl2 = (const float*)d_in[10];
  const int* srcp = edge;
  const int* dstp = edge + NE;

  char* w = (char*)d_ws;
  size_t off = 0;
  auto alloc = [&](size_t bytes) -> void* {
    void* p = w + off;
    off += (bytes + 255) & ~(size_t)255;
    return p;
  };
  int*    deg  = (int*)alloc(NN * 4);
  float*  dinv = (float*)alloc(NN * 4);
  ushort* ell  = (ushort*)alloc((size_t)NN * ELLW * 2);
  float*  tmp  = (float*)alloc((size_t)NN * HD * 4);
  float*  h1   = (float*)alloc((size_t)NN * HD * 4);
  float*  sums = (float*)alloc((size_t)NG * HD * 4);
  int*    cnt  = (int*)alloc(NG * 4);

  hipMemsetAsync(deg, 0, NN * 4, stream);
  hipMemsetAsync(sums, 0, (size_t)NG * HD * 4, stream);
  hipMemsetAsync(cnt, 0, NG * 4, stream);

  int blocks_per_vx = (NE + 256 * EPT - 1) / (256 * EPT);
  fill_k<<<blocks_per_vx * NVX, 256, 0, stream>>>(srcp, dstp, batch, deg, ell, cnt);
  dinv_k<<<(NN + 255) / 256, 256, 0, stream>>>(deg, dinv);

  gemm128_k<<<(NN + 63) / 64, 256, 0, stream>>>(x, W1, dinv, tmp);
  aggregate_k<false><<<(NN + 3) / 4, 256, 0, stream>>>(tmp, ell, deg, dinv, b1, h1, nullptr, nullptr);
  gemm128_k<<<(NN + 63) / 64, 256, 0, stream>>>(h1, W2, dinv, tmp);
  aggregate_k<true><<<(NN + 3) / 4, 256, 0, stream>>>(tmp, ell, deg, dinv, b2, nullptr, batch, sums);
  mlp_k<<<NG, 128, 0, stream>>>(sums, cnt, Wl1, bl1, Wl2, bl2, (float*)d_out);
}

// Round 11
// 318.520 us; speedup vs baseline: 1.0207x; 1.0207x over previous
//
#include <hip/hip_runtime.h>

#define NN 50000
#define NE 800000
#define HD 128
#define NG 256
#define ELLW 64

// ---------- build: deg count + ELL fill + batch count, one pass (R8 form) ----------
__global__ __launch_bounds__(256) void fill_k(const int* __restrict__ src, const int* __restrict__ dst,
                                              const int* __restrict__ batch,
                                              int* __restrict__ deg, ushort* __restrict__ ell,
                                              int* __restrict__ cnt) {
  int e = blockIdx.x * 256 + threadIdx.x;
  if (e < NE) {
    int d = dst[e];
    int p = atomicAdd(&deg[d], 1);
    if (p < ELLW) ell[(size_t)d * ELLW + p] = (ushort)src[e];
  }
  if (e < NN) atomicAdd(&cnt[batch[e]], 1);
}

__global__ __launch_bounds__(256) void dinv_k(const int* __restrict__ deg, float* __restrict__ dinv) {
  int n = blockIdx.x * 256 + threadIdx.x;
  if (n < NN) dinv[n] = 1.0f / sqrtf((float)(deg[n] + 1));  // +1: self-loop
}

// ---------- GEMM: out[r][c] = (sum_k X[r][k]*W[k][c]) * dinv[r] ----------
__global__ __launch_bounds__(256) void gemm128_k(const float* __restrict__ X, const float* __restrict__ W,
                                                 const float* __restrict__ dinv, float* __restrict__ out) {
  __shared__ float xs[64 * 128];
  int t = threadIdx.x;
  int row0 = blockIdx.x * 64;
  const float4* X4 = (const float4*)X;
  float4* xs4 = (float4*)xs;
#pragma unroll
  for (int i = 0; i < 8; ++i) {
    int idx = i * 256 + t;                 // 0..2047
    int r = row0 + (idx >> 5);
    if (r > NN - 1) r = NN - 1;
    xs4[idx] = X4[(size_t)r * 32 + (idx & 31)];
  }
  __syncthreads();
  int lane = t & 31;                        // cols lane*4 .. +3
  int rg = t >> 5;                          // rows rg*8 .. +7
  const float4* W4 = (const float4*)W;
  float acc[8][4] = {};
#pragma unroll 2
  for (int k = 0; k < 128; k += 4) {
    float4 b[4];
#pragma unroll
    for (int kk = 0; kk < 4; ++kk) b[kk] = W4[(size_t)(k + kk) * 32 + lane];
    float4 a[8];
#pragma unroll
    for (int i = 0; i < 8; ++i) a[i] = *(const float4*)&xs[(rg * 8 + i) * 128 + k];
#pragma unroll
    for (int i = 0; i < 8; ++i) {
      acc[i][0] = fmaf(a[i].x, b[0].x, acc[i][0]);
      acc[i][1] = fmaf(a[i].x, b[0].y, acc[i][1]);
      acc[i][2] = fmaf(a[i].x, b[0].z, acc[i][2]);
      acc[i][3] = fmaf(a[i].x, b[0].w, acc[i][3]);
      acc[i][0] = fmaf(a[i].y, b[1].x, acc[i][0]);
      acc[i][1] = fmaf(a[i].y, b[1].y, acc[i][1]);
      acc[i][2] = fmaf(a[i].y, b[1].z, acc[i][2]);
      acc[i][3] = fmaf(a[i].y, b[1].w, acc[i][3]);
      acc[i][0] = fmaf(a[i].z, b[2].x, acc[i][0]);
      acc[i][1] = fmaf(a[i].z, b[2].y, acc[i][1]);
      acc[i][2] = fmaf(a[i].z, b[2].z, acc[i][2]);
      acc[i][3] = fmaf(a[i].z, b[2].w, acc[i][3]);
      acc[i][0] = fmaf(a[i].w, b[3].x, acc[i][0]);
      acc[i][1] = fmaf(a[i].w, b[3].y, acc[i][1]);
      acc[i][2] = fmaf(a[i].w, b[3].z, acc[i][2]);
      acc[i][3] = fmaf(a[i].w, b[3].w, acc[i][3]);
    }
  }
#pragma unroll
  for (int i = 0; i < 8; ++i) {
    int r = row0 + rg * 8 + i;
    if (r < NN) {
      float d = dinv[r];
      float4 o = make_float4(acc[i][0] * d, acc[i][1] * d, acc[i][2] * d, acc[i][3] * d);
      *(float4*)&out[(size_t)r * 128 + lane * 4] = o;
    }
  }
}

// ---------- pull aggregation ----------
// One node per 64-lane wave; lane covers float2 (512B coalesced row reads).
// Indices from ELL (one ushort load/lane); uniform-lane __shfl -> SGPR-base
// gathers. Primary batch deepened to 16 loads in flight per lane.
template <bool POOL>
__global__ __launch_bounds__(256) void aggregate_k(const float* __restrict__ tmp2,
                                                   const ushort* __restrict__ ell, const int* __restrict__ deg,
                                                   const float* __restrict__ dinv, const float* __restrict__ bias,
                                                   float* __restrict__ out,
                                                   const int* __restrict__ batch, float* __restrict__ sums) {
  int wid = threadIdx.x >> 6;
  int lane = threadIdx.x & 63;
  int n = blockIdx.x * 4 + wid;
  if (n >= NN) return;
  const float2* T2 = (const float2*)tmp2;
  float2 acc = T2[(size_t)n * 64 + lane];  // self-loop term (already *dinv[n])
  int d = deg[n]; if (d > ELLW) d = ELLW;
  int idx = (int)ell[(size_t)n * ELLW + lane];  // lanes >= d hold garbage, never selected
  int j = 0;
  for (; j + 16 <= d; j += 16) {
    int s0 = __shfl(idx, j);
    int s1 = __shfl(idx, j + 1);
    int s2 = __shfl(idx, j + 2);
    int s3 = __shfl(idx, j + 3);
    int s4 = __shfl(idx, j + 4);
    int s5 = __shfl(idx, j + 5);
    int s6 = __shfl(idx, j + 6);
    int s7 = __shfl(idx, j + 7);
    int s8 = __shfl(idx, j + 8);
    int s9 = __shfl(idx, j + 9);
    int sa = __shfl(idx, j + 10);
    int sb = __shfl(idx, j + 11);
    int sc = __shfl(idx, j + 12);
    int sd = __shfl(idx, j + 13);
    int se = __shfl(idx, j + 14);
    int sf = __shfl(idx, j + 15);
    float2 v0 = T2[(size_t)s0 * 64 + lane];
    float2 v1 = T2[(size_t)s1 * 64 + lane];
    float2 v2 = T2[(size_t)s2 * 64 + lane];
    float2 v3 = T2[(size_t)s3 * 64 + lane];
    float2 v4 = T2[(size_t)s4 * 64 + lane];
    float2 v5 = T2[(size_t)s5 * 64 + lane];
    float2 v6 = T2[(size_t)s6 * 64 + lane];
    float2 v7 = T2[(size_t)s7 * 64 + lane];
    float2 v8 = T2[(size_t)s8 * 64 + lane];
    float2 v9 = T2[(size_t)s9 * 64 + lane];
    float2 va = T2[(size_t)sa * 64 + lane];
    float2 vb = T2[(size_t)sb * 64 + lane];
    float2 vc = T2[(size_t)sc * 64 + lane];
    float2 vd = T2[(size_t)sd * 64 + lane];
    float2 ve = T2[(size_t)se * 64 + lane];
    float2 vf = T2[(size_t)sf * 64 + lane];
    acc.x += (((v0.x + v1.x) + (v2.x + v3.x)) + ((v4.x + v5.x) + (v6.x + v7.x))) +
             (((v8.x + v9.x) + (va.x + vb.x)) + ((vc.x + vd.x) + (ve.x + vf.x)));
    acc.y += (((v0.y + v1.y) + (v2.y + v3.y)) + ((v4.y + v5.y) + (v6.y + v7.y))) +
             (((v8.y + v9.y) + (va.y + vb.y)) + ((vc.y + vd.y) + (ve.y + vf.y)));
  }
  for (; j + 8 <= d; j += 8) {
    int s0 = __shfl(idx, j);
    int s1 = __shfl(idx, j + 1);
    int s2 = __shfl(idx, j + 2);
    int s3 = __shfl(idx, j + 3);
    int s4 = __shfl(idx, j + 4);
    int s5 = __shfl(idx, j + 5);
    int s6 = __shfl(idx, j + 6);
    int s7 = __shfl(idx, j + 7);
    float2 v0 = T2[(size_t)s0 * 64 + lane];
    float2 v1 = T2[(size_t)s1 * 64 + lane];
    float2 v2 = T2[(size_t)s2 * 64 + lane];
    float2 v3 = T2[(size_t)s3 * 64 + lane];
    float2 v4 = T2[(size_t)s4 * 64 + lane];
    float2 v5 = T2[(size_t)s5 * 64 + lane];
    float2 v6 = T2[(size_t)s6 * 64 + lane];
    float2 v7 = T2[(size_t)s7 * 64 + lane];
    acc.x += ((v0.x + v1.x) + (v2.x + v3.x)) + ((v4.x + v5.x) + (v6.x + v7.x));
    acc.y += ((v0.y + v1.y) + (v2.y + v3.y)) + ((v4.y + v5.y) + (v6.y + v7.y));
  }
  for (; j < d; ++j) {
    int s0 = __shfl(idx, j);
    float2 v = T2[(size_t)s0 * 64 + lane];
    acc.x += v.x; acc.y += v.y;
  }
  float dv = dinv[n];
  float2 bb = ((const float2*)bias)[lane];
  float2 o;
  o.x = fmaxf(fmaf(acc.x, dv, bb.x), 0.0f);
  o.y = fmaxf(fmaf(acc.y, dv, bb.y), 0.0f);
  if (POOL) {
    int g = batch[n];
    float* sp = &sums[(size_t)g * HD + lane * 2];
    atomicAdd(sp + 0, o.x);
    atomicAdd(sp + 1, o.y);
  } else {
    ((float2*)out)[(size_t)n * 64 + lane] = o;
  }
}

// ---------- head ----------
__global__ __launch_bounds__(128) void mlp_k(const float* __restrict__ sums, const int* __restrict__ cnt,
                                             const float* __restrict__ Wl1, const float* __restrict__ bl1,
                                             const float* __restrict__ Wl2, const float* __restrict__ bl2,
                                             float* __restrict__ out) {
  __shared__ float gs[128];
  __shared__ float red[128];
  int g = blockIdx.x, t = threadIdx.x;
  int c = cnt[g]; if (c < 1) c = 1;
  gs[t] = sums[(size_t)g * HD + t] / (float)c;
  __syncthreads();
  float acc = bl1[t];
#pragma unroll 8
  for (int k = 0; k < 128; ++k) acc = fmaf(gs[k], Wl1[k * HD + t], acc);
  acc = fmaxf(acc, 0.0f);
  red[t] = acc * Wl2[t];
  __syncthreads();
  for (int off = 64; off > 0; off >>= 1) {
    if (t < off) red[t] += red[t + off];
    __syncthreads();
  }
  if (t == 0) out[g] = red[0] + bl2[0];
}

extern "C" void kernel_launch(void* const* d_in, const int* in_sizes, int n_in,
                              void* d_out, int out_size, void* d_ws, size_t ws_size,
                              hipStream_t stream) {
  const float* x   = (const float*)d_in[0];
  const int*   edge = (const int*)d_in[1];
  const int*   batch = (const int*)d_in[2];
  const float* W1  = (const float*)d_in[3];
  const float* b1  = (const float*)d_in[4];
  const float* W2  = (const float*)d_in[5];
  const float* b2  = (const float*)d_in[6];
  const float* Wl1 = (const float*)d_in[7];
  const float* bl1 = (const float*)d_in[8];
  const float* Wl2 = (const float*)d_in[9];
  const float* bl2 = (const float*)d_in[10];
  const int* srcp = edge;
  const int* dstp = edge + NE;

  char* w = (char*)d_ws;
  size_t off = 0;
  auto alloc = [&](size_t bytes) -> void* {
    void* p = w + off;
    off += (bytes + 255) & ~(size_t)255;
    return p;
  };
  int*    deg  = (int*)alloc(NN * 4);
  float*  dinv = (float*)alloc(NN * 4);
  ushort* ell  = (ushort*)alloc((size_t)NN * ELLW * 2);
  float*  tmp  = (float*)alloc((size_t)NN * HD * 4);
  float*  h1   = (float*)alloc((size_t)NN * HD * 4);
  float*  sums = (float*)alloc((size_t)NG * HD * 4);
  int*    cnt  = (int*)alloc(NG * 4);

  hipMemsetAsync(deg, 0, NN * 4, stream);
  hipMemsetAsync(sums, 0, (size_t)NG * HD * 4, stream);
  hipMemsetAsync(cnt, 0, NG * 4, stream);

  fill_k<<<(NE + 255) / 256, 256, 0, stream>>>(srcp, dstp, batch, deg, ell, cnt);
  dinv_k<<<(NN + 255) / 256, 256, 0, stream>>>(deg, dinv);

  gemm128_k<<<(NN + 63) / 64, 256, 0, stream>>>(x, W1, dinv, tmp);
  aggregate_k<false><<<(NN + 3) / 4, 256, 0, stream>>>(tmp, ell, deg, dinv, b1, h1, nullptr, nullptr);
  gemm128_k<<<(NN + 63) / 64, 256, 0, stream>>>(h1, W2, dinv, tmp);
  aggregate_k<true><<<(NN + 3) / 4, 256, 0, stream>>>(tmp, ell, deg, dinv, b2, nullptr, batch, sums);
  mlp_k<<<NG, 128, 0, stream>>>(sums, cnt, Wl1, bl1, Wl2, bl2, (float*)d_out);
}

// Round 12
// 272.710 us; speedup vs baseline: 1.1922x; 1.1680x over previous
//
#include <hip/hip_runtime.h>

#define NN 50000
#define NE 800000
#define HD 128
#define NG 256
#define ELLW 64

__device__ __forceinline__ unsigned f32_to_bf16_rne(float f) {
  unsigned u = __float_as_uint(f);
  return (u + 0x7fffu + ((u >> 16) & 1u)) >> 16;
}

// ---------- build: deg count + ELL fill + batch count, one pass (R8 form) ----------
__global__ __launch_bounds__(256) void fill_k(const int* __restrict__ src, const int* __restrict__ dst,
                                              const int* __restrict__ batch,
                                              int* __restrict__ deg, ushort* __restrict__ ell,
                                              int* __restrict__ cnt) {
  int e = blockIdx.x * 256 + threadIdx.x;
  if (e < NE) {
    int d = dst[e];
    int p = atomicAdd(&deg[d], 1);
    if (p < ELLW) ell[(size_t)d * ELLW + p] = (ushort)src[e];
  }
  if (e < NN) atomicAdd(&cnt[batch[e]], 1);
}

__global__ __launch_bounds__(256) void dinv_k(const int* __restrict__ deg, float* __restrict__ dinv) {
  int n = blockIdx.x * 256 + threadIdx.x;
  if (n < NN) dinv[n] = 1.0f / sqrtf((float)(deg[n] + 1));  // +1: self-loop
}

// ---------- GEMM: out_bf16[r][c] = bf16((sum_k X[r][k]*W[k][c]) * dinv[r]) ----------
// 64-row X tile in LDS; W from global (L2-hot). 8x4 register blocking.
// Output stored as bf16 (ushort), packed 4/lane -> 256B coalesced row segments.
__global__ __launch_bounds__(256) void gemm128_k(const float* __restrict__ X, const float* __restrict__ W,
                                                 const float* __restrict__ dinv, ushort* __restrict__ out) {
  __shared__ float xs[64 * 128];
  int t = threadIdx.x;
  int row0 = blockIdx.x * 64;
  const float4* X4 = (const float4*)X;
  float4* xs4 = (float4*)xs;
#pragma unroll
  for (int i = 0; i < 8; ++i) {
    int idx = i * 256 + t;                 // 0..2047
    int r = row0 + (idx >> 5);
    if (r > NN - 1) r = NN - 1;
    xs4[idx] = X4[(size_t)r * 32 + (idx & 31)];
  }
  __syncthreads();
  int lane = t & 31;                        // cols lane*4 .. +3
  int rg = t >> 5;                          // rows rg*8 .. +7
  const float4* W4 = (const float4*)W;
  float acc[8][4] = {};
#pragma unroll 2
  for (int k = 0; k < 128; k += 4) {
    float4 b[4];
#pragma unroll
    for (int kk = 0; kk < 4; ++kk) b[kk] = W4[(size_t)(k + kk) * 32 + lane];
    float4 a[8];
#pragma unroll
    for (int i = 0; i < 8; ++i) a[i] = *(const float4*)&xs[(rg * 8 + i) * 128 + k];
#pragma unroll
    for (int i = 0; i < 8; ++i) {
      acc[i][0] = fmaf(a[i].x, b[0].x, acc[i][0]);
      acc[i][1] = fmaf(a[i].x, b[0].y, acc[i][1]);
      acc[i][2] = fmaf(a[i].x, b[0].z, acc[i][2]);
      acc[i][3] = fmaf(a[i].x, b[0].w, acc[i][3]);
      acc[i][0] = fmaf(a[i].y, b[1].x, acc[i][0]);
      acc[i][1] = fmaf(a[i].y, b[1].y, acc[i][1]);
      acc[i][2] = fmaf(a[i].y, b[1].z, acc[i][2]);
      acc[i][3] = fmaf(a[i].y, b[1].w, acc[i][3]);
      acc[i][0] = fmaf(a[i].z, b[2].x, acc[i][0]);
      acc[i][1] = fmaf(a[i].z, b[2].y, acc[i][1]);
      acc[i][2] = fmaf(a[i].z, b[2].z, acc[i][2]);
      acc[i][3] = fmaf(a[i].z, b[2].w, acc[i][3]);
      acc[i][0] = fmaf(a[i].w, b[3].x, acc[i][0]);
      acc[i][1] = fmaf(a[i].w, b[3].y, acc[i][1]);
      acc[i][2] = fmaf(a[i].w, b[3].z, acc[i][2]);
      acc[i][3] = fmaf(a[i].w, b[3].w, acc[i][3]);
    }
  }
#pragma unroll
  for (int i = 0; i < 8; ++i) {
    int r = row0 + rg * 8 + i;
    if (r < NN) {
      float d = dinv[r];
      ushort4 o;
      o.x = (ushort)f32_to_bf16_rne(acc[i][0] * d);
      o.y = (ushort)f32_to_bf16_rne(acc[i][1] * d);
      o.z = (ushort)f32_to_bf16_rne(acc[i][2] * d);
      o.w = (ushort)f32_to_bf16_rne(acc[i][3] * d);
      *(ushort4*)&out[(size_t)r * 128 + lane * 4] = o;
    }
  }
}

// ---------- pull aggregation ----------
// One node per 64-lane wave; lane covers one uint = 2 bf16 (row = 256B, one
// coalesced access / 4 lines per neighbor row). Indices from ELL (one ushort
// load/lane); uniform-lane __shfl -> SGPR-base gathers, 8-deep batches.
// Accumulation in f32 (bf16->f32 expand = shift).
template <bool POOL>
__global__ __launch_bounds__(256) void aggregate_k(const ushort* __restrict__ tmp2,
                                                   const ushort* __restrict__ ell, const int* __restrict__ deg,
                                                   const float* __restrict__ dinv, const float* __restrict__ bias,
                                                   float* __restrict__ out,
                                                   const int* __restrict__ batch, float* __restrict__ sums) {
  int wid = threadIdx.x >> 6;
  int lane = threadIdx.x & 63;
  int n = blockIdx.x * 4 + wid;
  if (n >= NN) return;
  const uint* TU = (const uint*)tmp2;          // one uint = cols {2*lane, 2*lane+1}
  uint sv = TU[(size_t)n * 64 + lane];         // self-loop term (already *dinv[n])
  float2 acc;
  acc.x = __uint_as_float(sv << 16);
  acc.y = __uint_as_float(sv & 0xffff0000u);
  int d = deg[n]; if (d > ELLW) d = ELLW;
  int idx = (int)ell[(size_t)n * ELLW + lane];  // lanes >= d hold garbage, never selected
  int j = 0;
  for (; j + 8 <= d; j += 8) {
    int s0 = __shfl(idx, j);
    int s1 = __shfl(idx, j + 1);
    int s2 = __shfl(idx, j + 2);
    int s3 = __shfl(idx, j + 3);
    int s4 = __shfl(idx, j + 4);
    int s5 = __shfl(idx, j + 5);
    int s6 = __shfl(idx, j + 6);
    int s7 = __shfl(idx, j + 7);
    uint v0 = TU[(size_t)s0 * 64 + lane];
    uint v1 = TU[(size_t)s1 * 64 + lane];
    uint v2 = TU[(size_t)s2 * 64 + lane];
    uint v3 = TU[(size_t)s3 * 64 + lane];
    uint v4 = TU[(size_t)s4 * 64 + lane];
    uint v5 = TU[(size_t)s5 * 64 + lane];
    uint v6 = TU[(size_t)s6 * 64 + lane];
    uint v7 = TU[(size_t)s7 * 64 + lane];
    float x0 = __uint_as_float(v0 << 16), y0 = __uint_as_float(v0 & 0xffff0000u);
    float x1 = __uint_as_float(v1 << 16), y1 = __uint_as_float(v1 & 0xffff0000u);
    float x2 = __uint_as_float(v2 << 16), y2 = __uint_as_float(v2 & 0xffff0000u);
    float x3 = __uint_as_float(v3 << 16), y3 = __uint_as_float(v3 & 0xffff0000u);
    float x4 = __uint_as_float(v4 << 16), y4 = __uint_as_float(v4 & 0xffff0000u);
    float x5 = __uint_as_float(v5 << 16), y5 = __uint_as_float(v5 & 0xffff0000u);
    float x6 = __uint_as_float(v6 << 16), y6 = __uint_as_float(v6 & 0xffff0000u);
    float x7 = __uint_as_float(v7 << 16), y7 = __uint_as_float(v7 & 0xffff0000u);
    acc.x += ((x0 + x1) + (x2 + x3)) + ((x4 + x5) + (x6 + x7));
    acc.y += ((y0 + y1) + (y2 + y3)) + ((y4 + y5) + (y6 + y7));
  }
  for (; j < d; ++j) {
    int s0 = __shfl(idx, j);
    uint v = TU[(size_t)s0 * 64 + lane];
    acc.x += __uint_as_float(v << 16);
    acc.y += __uint_as_float(v & 0xffff0000u);
  }
  float dv = dinv[n];
  float2 bb = ((const float2*)bias)[lane];
  float2 o;
  o.x = fmaxf(fmaf(acc.x, dv, bb.x), 0.0f);
  o.y = fmaxf(fmaf(acc.y, dv, bb.y), 0.0f);
  if (POOL) {
    int g = batch[n];
    float* sp = &sums[(size_t)g * HD + lane * 2];
    atomicAdd(sp + 0, o.x);
    atomicAdd(sp + 1, o.y);
  } else {
    ((float2*)out)[(size_t)n * 64 + lane] = o;
  }
}

// ---------- head ----------
__global__ __launch_bounds__(128) void mlp_k(const float* __restrict__ sums, const int* __restrict__ cnt,
                                             const float* __restrict__ Wl1, const float* __restrict__ bl1,
                                             const float* __restrict__ Wl2, const float* __restrict__ bl2,
                                             float* __restrict__ out) {
  __shared__ float gs[128];
  __shared__ float red[128];
  int g = blockIdx.x, t = threadIdx.x;
  int c = cnt[g]; if (c < 1) c = 1;
  gs[t] = sums[(size_t)g * HD + t] / (float)c;
  __syncthreads();
  float acc = bl1[t];
#pragma unroll 8
  for (int k = 0; k < 128; ++k) acc = fmaf(gs[k], Wl1[k * HD + t], acc);
  acc = fmaxf(acc, 0.0f);
  red[t] = acc * Wl2[t];
  __syncthreads();
  for (int off = 64; off > 0; off >>= 1) {
    if (t < off) red[t] += red[t + off];
    __syncthreads();
  }
  if (t == 0) out[g] = red[0] + bl2[0];
}

extern "C" void kernel_launch(void* const* d_in, const int* in_sizes, int n_in,
                              void* d_out, int out_size, void* d_ws, size_t ws_size,
                              hipStream_t stream) {
  const float* x   = (const float*)d_in[0];
  const int*   edge = (const int*)d_in[1];
  const int*   batch = (const int*)d_in[2];
  const float* W1  = (const float*)d_in[3];
  const float* b1  = (const float*)d_in[4];
  const float* W2  = (const float*)d_in[5];
  const float* b2  = (const float*)d_in[6];
  const float* Wl1 = (const float*)d_in[7];
  const float* bl1 = (const float*)d_in[8];
  const float* Wl2 = (const float*)d_in[9];
  const float* bl2 = (const float*)d_in[10];
  const int* srcp = edge;
  const int* dstp = edge + NE;

  char* w = (char*)d_ws;
  size_t off = 0;
  auto alloc = [&](size_t bytes) -> void* {
    void* p = w + off;
    off += (bytes + 255) & ~(size_t)255;
    return p;
  };
  int*    deg  = (int*)alloc(NN * 4);
  float*  dinv = (float*)alloc(NN * 4);
  ushort* ell  = (ushort*)alloc((size_t)NN * ELLW * 2);
  ushort* tmp  = (ushort*)alloc((size_t)NN * HD * 2);   // bf16 gather operand
  float*  h1   = (float*)alloc((size_t)NN * HD * 4);
  float*  sums = (float*)alloc((size_t)NG * HD * 4);
  int*    cnt  = (int*)alloc(NG * 4);

  hipMemsetAsync(deg, 0, NN * 4, stream);
  hipMemsetAsync(sums, 0, (size_t)NG * HD * 4, stream);
  hipMemsetAsync(cnt, 0, NG * 4, stream);

  fill_k<<<(NE + 255) / 256, 256, 0, stream>>>(srcp, dstp, batch, deg, ell, cnt);
  dinv_k<<<(NN + 255) / 256, 256, 0, stream>>>(deg, dinv);

  gemm128_k<<<(NN + 63) / 64, 256, 0, stream>>>(x, W1, dinv, tmp);
  aggregate_k<false><<<(NN + 3) / 4, 256, 0, stream>>>(tmp, ell, deg, dinv, b1, h1, nullptr, nullptr);
  gemm128_k<<<(NN + 63) / 64, 256, 0, stream>>>(h1, W2, dinv, tmp);
  aggregate_k<true><<<(NN + 3) / 4, 256, 0, stream>>>(tmp, ell, deg, dinv, b2, nullptr, batch, sums);
  mlp_k<<<NG, 128, 0, stream>>>(sums, cnt, Wl1, bl1, Wl2, bl2, (float*)d_out);
}